// Round 1
// baseline (78308.643 us; speedup 1.0000x reference)
//
#include <hip/hip_runtime.h>

#define Tn 512
#define Bn 512
#define Fn 128
#define Gn 12
#define Hn 768
#define XW 140   // F+G
#define D1n 512
#define An 128
#define NT 512
#define NB 256

using bfrag = __attribute__((ext_vector_type(8))) short;   // 8 bf16 (4 VGPRs)
using f32x4 = __attribute__((ext_vector_type(4))) float;

__device__ __forceinline__ unsigned short f2bf(float x) {
  union { float f; unsigned int u; } v; v.f = x;
  unsigned int r = v.u + 0x7FFFu + ((v.u >> 16) & 1u);   // RNE
  return (unsigned short)(r >> 16);
}
__device__ __forceinline__ float bf2f(unsigned short h) {
  union { unsigned int u; float f; } v; v.u = ((unsigned int)h) << 16; return v.f;
}
__device__ __forceinline__ float sigmoid_f(float x) { return 1.f / (1.f + __expf(-x)); }
__device__ __forceinline__ float tanh_f(float x) {
  x = fminf(fmaxf(x, -15.f), 15.f);
  float e = __expf(2.f * x);
  return (e - 1.f) / (e + 1.f);
}
__device__ __forceinline__ f32x4 MFMA(bfrag a, bfrag b, f32x4 c) {
  return __builtin_amdgcn_mfma_f32_16x16x32_bf16(a, b, c, 0, 0, 0);
}

// ---------------- two-level grid barrier (256 blocks resident) ----------------
// barb layout (ints): [0..255] 8 sub-counters at stride 32; [256] root; [288] gen
__device__ __forceinline__ void grid_barrier(int* barb) {
  __syncthreads();
  if (threadIdx.x == 0) {
    __threadfence();                       // release: wb L2 so other XCDs see our stores
    int* gen  = barb + 288;
    int* root = barb + 256;
    int* subc = barb + ((blockIdx.x & 7) << 5);
    int g = __hip_atomic_load(gen, __ATOMIC_RELAXED, __HIP_MEMORY_SCOPE_AGENT);
    int prev = __hip_atomic_fetch_add(subc, 1, __ATOMIC_ACQ_REL, __HIP_MEMORY_SCOPE_AGENT);
    if (prev == 31) {
      __hip_atomic_store(subc, 0, __ATOMIC_RELAXED, __HIP_MEMORY_SCOPE_AGENT);
      int rprev = __hip_atomic_fetch_add(root, 1, __ATOMIC_ACQ_REL, __HIP_MEMORY_SCOPE_AGENT);
      if (rprev == 7) {
        __hip_atomic_store(root, 0, __ATOMIC_RELAXED, __HIP_MEMORY_SCOPE_AGENT);
        __hip_atomic_store(gen, g + 1, __ATOMIC_RELEASE, __HIP_MEMORY_SCOPE_AGENT);
      } else {
        while (__hip_atomic_load(gen, __ATOMIC_RELAXED, __HIP_MEMORY_SCOPE_AGENT) == g)
          __builtin_amdgcn_s_sleep(2);
      }
    } else {
      while (__hip_atomic_load(gen, __ATOMIC_RELAXED, __HIP_MEMORY_SCOPE_AGENT) == g)
        __builtin_amdgcn_s_sleep(2);
    }
    __threadfence();                       // acquire: invalidate L1/L2 before reading remote data
  }
  __syncthreads();
}

// ---------------- setup: bf16 weight conversion + state zeroing ----------------
struct SetupP {
  const float *Wih1f, *Whh1f, *Wih2f, *Whh2f, *l1wf, *l2wf, *bih1, *bhh1, *bih2, *bhh2;
  unsigned short *Wih1, *Whh1, *Wih2, *Whh2, *l1w, *l2w;
  float *b1s, *b2s;
  unsigned short *h1hi, *h1lo, *h2hi, *h2lo;
  float *c1, *c2;
  int* bar;
};

__global__ void setup_kernel(SetupP sp) {
  const size_t gtid = (size_t)blockIdx.x * blockDim.x + threadIdx.x;
  const size_t gs = (size_t)gridDim.x * blockDim.x;
  for (size_t i = gtid; i < 3072u*128u; i += gs) sp.Wih1[i] = f2bf(sp.Wih1f[i]);
  for (size_t i = gtid; i < 3072u*768u; i += gs) sp.Whh1[i] = f2bf(sp.Whh1f[i]);
  for (size_t i = gtid; i < 3072u*768u; i += gs) sp.Wih2[i] = f2bf(sp.Wih2f[i]);
  for (size_t i = gtid; i < 3072u*768u; i += gs) sp.Whh2[i] = f2bf(sp.Whh2f[i]);
  for (size_t i = gtid; i < 512u*768u; i += gs) {
    size_t c = i / 768u, k = i - c * 768u;
    sp.l1w[i] = f2bf(sp.l1wf[c * 780u + k]);
  }
  for (size_t i = gtid; i < 128u*512u; i += gs) sp.l2w[i] = f2bf(sp.l2wf[i]);
  for (size_t i = gtid; i < 3072u; i += gs) {
    sp.b1s[i] = sp.bih1[i] + sp.bhh1[i];
    sp.b2s[i] = sp.bih2[i] + sp.bhh2[i];
  }
  for (size_t i = gtid; i < 2u*512u*768u; i += gs) {   // both parities
    sp.h1hi[i] = 0; sp.h1lo[i] = 0; sp.h2hi[i] = 0; sp.h2lo[i] = 0;
  }
  for (size_t i = gtid; i < 512u*768u; i += gs) { sp.c1[i] = 0.f; sp.c2[i] = 0.f; }
  for (size_t i = gtid; i < 512u; i += gs) sp.bar[i] = 0;
}

// ---------------- main persistent kernel ----------------
struct MainP {
  const float* x;
  const float* l1w_f; const float* l1b; const float* l2b;
  const unsigned short *Wih1, *Whh1, *Wih2, *Whh2, *l1w, *l2w;
  const float *b1s, *b2s;
  unsigned short *h1hi, *h1lo, *h2hi, *h2lo, *a1hi, *a1lo;
  float *c1, *c2, *out;
  int* bar;
};

__global__ __launch_bounds__(NT, 2) void lstm_main(MainP P) {
  const int tid = threadIdx.x;
  const int bid = blockIdx.x;
  const int lane = tid & 63;
  const int wv = tid >> 6;          // 0..7
  const int lr = lane & 15;
  const int lk = lane >> 4;         // 0..3, k-chunk = lk*8

  __shared__ __align__(16) char smem[24576];
  unsigned short (*s_xhi)[Fn] = (unsigned short(*)[Fn])smem;            // 8KB
  unsigned short (*s_xlo)[Fn] = (unsigned short(*)[Fn])(smem + 8192);   // 8KB
  float (*s_gbuf)[32][48]      = (float(*)[32][48])smem;                // [4][32][48] 24KB
  float (*s_red2)[4][16][16]   = (float(*)[4][16][16])smem;             // [2][4][16][16] 8KB
  float (*s_red)[16][16]       = (float(*)[16][16])smem;                // [8][16][16] 8KB

  // phase1/2 mapping: 16 row-tiles(32) x 16 unit-tiles(48)
  const int rb = (bid >> 4) * 32;
  const int ub = (bid & 15) * 48;
  const int g  = wv & 3;            // gate
  const int rh = wv >> 2;           // row half
  const int r0 = rh * 16 + lr;
  const int grow = rb + r0;
  // phase3 mapping: 16 row-tiles(32) x 16 col-tiles(32)
  const int cb3 = (bid & 15) * 32;
  const int fr3 = (wv & 3) >> 1, fc3 = (wv & 3) & 1, kh3 = wv >> 2;
  // phase4 mapping: 32 row-tiles(16) x 8 col-tiles(16)
  const int rb4 = (bid >> 3) * 16;
  const int cb4 = (bid & 7) * 16;

  for (int t = 0; t < Tn; ++t) {
    const int p = t & 1;
    const unsigned short* h1hi_r = P.h1hi + (size_t)p * (Bn * Hn);
    const unsigned short* h1lo_r = P.h1lo + (size_t)p * (Bn * Hn);
    unsigned short* h1hi_w = P.h1hi + (size_t)(p ^ 1) * (Bn * Hn);
    unsigned short* h1lo_w = P.h1lo + (size_t)(p ^ 1) * (Bn * Hn);
    const unsigned short* h2hi_r = P.h2hi + (size_t)p * (Bn * Hn);
    const unsigned short* h2lo_r = P.h2lo + (size_t)p * (Bn * Hn);
    unsigned short* h2hi_w = P.h2hi + (size_t)(p ^ 1) * (Bn * Hn);
    unsigned short* h2lo_w = P.h2lo + (size_t)(p ^ 1) * (Bn * Hn);

    // ================= PHASE 1: gates1 + cell1 =================
    for (int idx = tid; idx < 32 * Fn; idx += NT) {
      int r = idx >> 7, k = idx & 127;
      float v = P.x[((size_t)t * Bn + rb + r) * XW + k];
      unsigned short hi = f2bf(v);
      unsigned short lo = f2bf(v - bf2f(hi));
      int ks = (((k >> 3) ^ (r & 7)) << 3) | (k & 7);   // XOR-swizzle 16B granules
      s_xhi[r][ks] = hi;
      s_xlo[r][ks] = lo;
    }
    __syncthreads();

    f32x4 a0 = {0.f,0.f,0.f,0.f}, a1 = {0.f,0.f,0.f,0.f}, a2 = {0.f,0.f,0.f,0.f};
    {
      const int colg = g * Hn + ub;
      // x part (K=128), A from swizzled LDS
      #pragma unroll
      for (int kb = 0; kb < Fn; kb += 32) {
        int kc = (kb >> 3) + lk;
        bfrag ahi = *(const bfrag*)&s_xhi[r0][(kc ^ (r0 & 7)) << 3];
        bfrag alo = *(const bfrag*)&s_xlo[r0][(kc ^ (r0 & 7)) << 3];
        const unsigned short* wp = P.Wih1 + (size_t)(colg + lr) * Fn + kb + lk * 8;
        bfrag b0 = *(const bfrag*)(wp);
        bfrag b1 = *(const bfrag*)(wp + (size_t)16 * Fn);
        bfrag b2 = *(const bfrag*)(wp + (size_t)32 * Fn);
        a0 = MFMA(ahi, b0, a0); a0 = MFMA(alo, b0, a0);
        a1 = MFMA(ahi, b1, a1); a1 = MFMA(alo, b1, a1);
        a2 = MFMA(ahi, b2, a2); a2 = MFMA(alo, b2, a2);
      }
      // h part (K=768), A hi/lo direct from global
      const unsigned short* ah = h1hi_r + (size_t)grow * Hn + lk * 8;
      const unsigned short* al = h1lo_r + (size_t)grow * Hn + lk * 8;
      const unsigned short* wb = P.Whh1 + (size_t)(colg + lr) * Hn + lk * 8;
      #pragma unroll 2
      for (int kb = 0; kb < Hn; kb += 32) {
        bfrag ahi = *(const bfrag*)(ah + kb);
        bfrag alo = *(const bfrag*)(al + kb);
        bfrag b0 = *(const bfrag*)(wb + kb);
        bfrag b1 = *(const bfrag*)(wb + kb + (size_t)16 * Hn);
        bfrag b2 = *(const bfrag*)(wb + kb + (size_t)32 * Hn);
        a0 = MFMA(ahi, b0, a0); a0 = MFMA(alo, b0, a0);
        a1 = MFMA(ahi, b1, a1); a1 = MFMA(alo, b1, a1);
        a2 = MFMA(ahi, b2, a2); a2 = MFMA(alo, b2, a2);
      }
    }
    __syncthreads();   // all waves done with s_xhi/s_xlo before gbuf overwrite
    {
      int rw = rh * 16 + lk * 4;
      #pragma unroll
      for (int j = 0; j < 4; ++j) {
        s_gbuf[g][rw + j][lr]      = a0[j];
        s_gbuf[g][rw + j][16 + lr] = a1[j];
        s_gbuf[g][rw + j][32 + lr] = a2[j];
      }
    }
    __syncthreads();
    for (int e = tid; e < 32 * 48; e += NT) {
      int r = e / 48, u = e - r * 48;
      int gu = ub + u;
      size_t cidx = (size_t)(rb + r) * Hn + gu;
      float gi = s_gbuf[0][r][u] + P.b1s[gu];
      float gf = s_gbuf[1][r][u] + P.b1s[Hn + gu];
      float gg = s_gbuf[2][r][u] + P.b1s[2 * Hn + gu];
      float go = s_gbuf[3][r][u] + P.b1s[3 * Hn + gu];
      float co = P.c1[cidx];
      float cn = sigmoid_f(gf) * co + sigmoid_f(gi) * tanh_f(gg);
      float hn = sigmoid_f(go) * tanh_f(cn);
      P.c1[cidx] = cn;
      unsigned short hi = f2bf(hn);
      h1hi_w[cidx] = hi;
      h1lo_w[cidx] = f2bf(hn - bf2f(hi));
    }
    grid_barrier(P.bar);

    // ================= PHASE 2: gates2 + cell2 =================
    f32x4 c0 = {0.f,0.f,0.f,0.f}, c1a = {0.f,0.f,0.f,0.f}, c2a = {0.f,0.f,0.f,0.f};
    {
      const int colg = g * Hn + ub;
      const unsigned short* ah1 = h1hi_w + (size_t)grow * Hn + lk * 8;  // current h1
      const unsigned short* al1 = h1lo_w + (size_t)grow * Hn + lk * 8;
      const unsigned short* wb1 = P.Wih2 + (size_t)(colg + lr) * Hn + lk * 8;
      #pragma unroll 2
      for (int kb = 0; kb < Hn; kb += 32) {
        bfrag ahi = *(const bfrag*)(ah1 + kb);
        bfrag alo = *(const bfrag*)(al1 + kb);
        bfrag b0 = *(const bfrag*)(wb1 + kb);
        bfrag b1 = *(const bfrag*)(wb1 + kb + (size_t)16 * Hn);
        bfrag b2 = *(const bfrag*)(wb1 + kb + (size_t)32 * Hn);
        c0 = MFMA(ahi, b0, c0); c0 = MFMA(alo, b0, c0);
        c1a = MFMA(ahi, b1, c1a); c1a = MFMA(alo, b1, c1a);
        c2a = MFMA(ahi, b2, c2a); c2a = MFMA(alo, b2, c2a);
      }
      const unsigned short* ah2 = h2hi_r + (size_t)grow * Hn + lk * 8;  // previous h2
      const unsigned short* al2 = h2lo_r + (size_t)grow * Hn + lk * 8;
      const unsigned short* wb2 = P.Whh2 + (size_t)(colg + lr) * Hn + lk * 8;
      #pragma unroll 2
      for (int kb = 0; kb < Hn; kb += 32) {
        bfrag ahi = *(const bfrag*)(ah2 + kb);
        bfrag alo = *(const bfrag*)(al2 + kb);
        bfrag b0 = *(const bfrag*)(wb2 + kb);
        bfrag b1 = *(const bfrag*)(wb2 + kb + (size_t)16 * Hn);
        bfrag b2 = *(const bfrag*)(wb2 + kb + (size_t)32 * Hn);
        c0 = MFMA(ahi, b0, c0); c0 = MFMA(alo, b0, c0);
        c1a = MFMA(ahi, b1, c1a); c1a = MFMA(alo, b1, c1a);
        c2a = MFMA(ahi, b2, c2a); c2a = MFMA(alo, b2, c2a);
      }
    }
    {
      int rw = rh * 16 + lk * 4;
      #pragma unroll
      for (int j = 0; j < 4; ++j) {
        s_gbuf[g][rw + j][lr]      = c0[j];
        s_gbuf[g][rw + j][16 + lr] = c1a[j];
        s_gbuf[g][rw + j][32 + lr] = c2a[j];
      }
    }
    __syncthreads();
    for (int e = tid; e < 32 * 48; e += NT) {
      int r = e / 48, u = e - r * 48;
      int gu = ub + u;
      size_t cidx = (size_t)(rb + r) * Hn + gu;
      float gi = s_gbuf[0][r][u] + P.b2s[gu];
      float gf = s_gbuf[1][r][u] + P.b2s[Hn + gu];
      float gg = s_gbuf[2][r][u] + P.b2s[2 * Hn + gu];
      float go = s_gbuf[3][r][u] + P.b2s[3 * Hn + gu];
      float co = P.c2[cidx];
      float cn = sigmoid_f(gf) * co + sigmoid_f(gi) * tanh_f(gg);
      float hn = sigmoid_f(go) * tanh_f(cn);
      P.c2[cidx] = cn;
      unsigned short hi = f2bf(hn);
      h2hi_w[cidx] = hi;
      h2lo_w[cidx] = f2bf(hn - bf2f(hi));
    }
    grid_barrier(P.bar);

    // ================= PHASE 3: l1 + selu -> a1 =================
    f32x4 a3 = {0.f,0.f,0.f,0.f};
    {
      const int arow = rb + fr3 * 16 + lr;
      const int col = cb3 + fc3 * 16 + lr;
      const unsigned short* ah = h2hi_w + (size_t)arow * Hn + lk * 8;
      const unsigned short* al = h2lo_w + (size_t)arow * Hn + lk * 8;
      const unsigned short* wb = P.l1w + (size_t)col * Hn + lk * 8;
      #pragma unroll 2
      for (int kb = kh3 * 384; kb < kh3 * 384 + 384; kb += 32) {
        bfrag ahi = *(const bfrag*)(ah + kb);
        bfrag alo = *(const bfrag*)(al + kb);
        bfrag bw = *(const bfrag*)(wb + kb);
        a3 = MFMA(ahi, bw, a3); a3 = MFMA(alo, bw, a3);
      }
    }
    {
      #pragma unroll
      for (int j = 0; j < 4; ++j) s_red2[kh3][wv & 3][lk * 4 + j][lr] = a3[j];
    }
    __syncthreads();
    for (int e = tid; e < 32 * 32; e += NT) {
      int r = e >> 5, cl = e & 31;
      int f = ((r >> 4) << 1) + (cl >> 4);
      float v = s_red2[0][f][r & 15][cl & 15] + s_red2[1][f][r & 15][cl & 15];
      int row = rb + r, col = cb3 + cl;
      v += P.l1b[col];
      const float* xg = P.x + ((size_t)t * Bn + row) * XW + Fn;   // gen features, fp32
      const float* wg = P.l1w_f + (size_t)col * 780 + 768;
      #pragma unroll
      for (int q = 0; q < Gn; ++q) v += xg[q] * wg[q];
      float s = (v > 0.f) ? 1.0507009873554805f * v
                          : 1.7580993408473766f * (__expf(v) - 1.f);
      unsigned short hi = f2bf(s);
      P.a1hi[(size_t)row * D1n + col] = hi;
      P.a1lo[(size_t)row * D1n + col] = f2bf(s - bf2f(hi));
    }
    grid_barrier(P.bar);

    // ================= PHASE 4: l2 -> out[t] =================
    f32x4 a4 = {0.f,0.f,0.f,0.f};
    {
      const unsigned short* ah = P.a1hi + (size_t)(rb4 + lr) * D1n + lk * 8;
      const unsigned short* al = P.a1lo + (size_t)(rb4 + lr) * D1n + lk * 8;
      const unsigned short* wb = P.l2w + (size_t)(cb4 + lr) * D1n + lk * 8;
      #pragma unroll
      for (int kb = wv * 64; kb < wv * 64 + 64; kb += 32) {
        bfrag ahi = *(const bfrag*)(ah + kb);
        bfrag alo = *(const bfrag*)(al + kb);
        bfrag bw = *(const bfrag*)(wb + kb);
        a4 = MFMA(ahi, bw, a4); a4 = MFMA(alo, bw, a4);
      }
    }
    #pragma unroll
    for (int j = 0; j < 4; ++j) s_red[wv][lk * 4 + j][lr] = a4[j];
    __syncthreads();
    if (tid < 256) {
      int rl = tid >> 4, cl = tid & 15;
      float v = P.l2b[cb4 + cl];
      #pragma unroll
      for (int w = 0; w < 8; ++w) v += s_red[w][rl][cl];
      P.out[(size_t)t * (Bn * An) + (size_t)(rb4 + rl) * An + cb4 + cl] = v;
    }
    __syncthreads();   // protect smem before next-iteration LDS writes
  }
}

// ---------------- launch ----------------
extern "C" void kernel_launch(void* const* d_in, const int* in_sizes, int n_in,
                              void* d_out, int out_size, void* d_ws, size_t ws_size,
                              hipStream_t stream) {
  const float* x     = (const float*)d_in[0];
  const float* Wih1f = (const float*)d_in[1];
  const float* Whh1f = (const float*)d_in[2];
  const float* bih1  = (const float*)d_in[3];
  const float* bhh1  = (const float*)d_in[4];
  const float* Wih2f = (const float*)d_in[5];
  const float* Whh2f = (const float*)d_in[6];
  const float* bih2  = (const float*)d_in[7];
  const float* bhh2  = (const float*)d_in[8];
  const float* l1wf  = (const float*)d_in[9];
  const float* l1b   = (const float*)d_in[10];
  const float* l2wf  = (const float*)d_in[11];
  const float* l2b   = (const float*)d_in[12];

  char* ws = (char*)d_ws;
  constexpr size_t o_Wih1 = 0;
  constexpr size_t o_Whh1 = o_Wih1 + (size_t)3072 * 128 * 2;
  constexpr size_t o_Wih2 = o_Whh1 + (size_t)3072 * 768 * 2;
  constexpr size_t o_Whh2 = o_Wih2 + (size_t)3072 * 768 * 2;
  constexpr size_t o_l1w  = o_Whh2 + (size_t)3072 * 768 * 2;
  constexpr size_t o_l2w  = o_l1w + (size_t)512 * 768 * 2;
  constexpr size_t o_b1s  = o_l2w + (size_t)128 * 512 * 2;
  constexpr size_t o_b2s  = o_b1s + (size_t)3072 * 4;
  constexpr size_t o_h1hi = o_b2s + (size_t)3072 * 4;
  constexpr size_t o_h1lo = o_h1hi + (size_t)2 * 512 * 768 * 2;
  constexpr size_t o_h2hi = o_h1lo + (size_t)2 * 512 * 768 * 2;
  constexpr size_t o_h2lo = o_h2hi + (size_t)2 * 512 * 768 * 2;
  constexpr size_t o_c1   = o_h2lo + (size_t)2 * 512 * 768 * 2;
  constexpr size_t o_c2   = o_c1 + (size_t)512 * 768 * 4;
  constexpr size_t o_a1hi = o_c2 + (size_t)512 * 768 * 4;
  constexpr size_t o_a1lo = o_a1hi + (size_t)512 * 512 * 2;
  constexpr size_t o_bar  = o_a1lo + (size_t)512 * 512 * 2;

  SetupP sp;
  sp.Wih1f = Wih1f; sp.Whh1f = Whh1f; sp.Wih2f = Wih2f; sp.Whh2f = Whh2f;
  sp.l1wf = l1wf; sp.l2wf = l2wf; sp.bih1 = bih1; sp.bhh1 = bhh1; sp.bih2 = bih2; sp.bhh2 = bhh2;
  sp.Wih1 = (unsigned short*)(ws + o_Wih1);
  sp.Whh1 = (unsigned short*)(ws + o_Whh1);
  sp.Wih2 = (unsigned short*)(ws + o_Wih2);
  sp.Whh2 = (unsigned short*)(ws + o_Whh2);
  sp.l1w  = (unsigned short*)(ws + o_l1w);
  sp.l2w  = (unsigned short*)(ws + o_l2w);
  sp.b1s  = (float*)(ws + o_b1s);
  sp.b2s  = (float*)(ws + o_b2s);
  sp.h1hi = (unsigned short*)(ws + o_h1hi);
  sp.h1lo = (unsigned short*)(ws + o_h1lo);
  sp.h2hi = (unsigned short*)(ws + o_h2hi);
  sp.h2lo = (unsigned short*)(ws + o_h2lo);
  sp.c1   = (float*)(ws + o_c1);
  sp.c2   = (float*)(ws + o_c2);
  sp.bar  = (int*)(ws + o_bar);
  setup_kernel<<<2048, 256, 0, stream>>>(sp);

  MainP mp;
  mp.x = x; mp.l1w_f = l1wf; mp.l1b = l1b; mp.l2b = l2b;
  mp.Wih1 = sp.Wih1; mp.Whh1 = sp.Whh1; mp.Wih2 = sp.Wih2; mp.Whh2 = sp.Whh2;
  mp.l1w = sp.l1w; mp.l2w = sp.l2w;
  mp.b1s = sp.b1s; mp.b2s = sp.b2s;
  mp.h1hi = sp.h1hi; mp.h1lo = sp.h1lo; mp.h2hi = sp.h2hi; mp.h2lo = sp.h2lo;
  mp.a1hi = (unsigned short*)(ws + o_a1hi);
  mp.a1lo = (unsigned short*)(ws + o_a1lo);
  mp.c1 = sp.c1; mp.c2 = sp.c2;
  mp.out = (float*)d_out;
  mp.bar = sp.bar;
  lstm_main<<<NB, NT, 0, stream>>>(mp);
}